// Round 19
// baseline (633.975 us; speedup 1.0000x reference)
//
#include <hip/hip_runtime.h>
#include <hip/hip_bf16.h>
#include <stdint.h>

// Problem constants
#define TLEN 4096
#define DMm  2048
#define DD   4096
#define DGg  512
#define BT   8192          // B*T
#define DW   16384         // D*W

typedef __attribute__((ext_vector_type(8))) short bf16x8;
typedef __attribute__((ext_vector_type(4))) float f32x4;

__device__ __forceinline__ unsigned short f2bf(float f) {
    union { float f; unsigned u; } c; c.f = f;
    unsigned u = c.u;
    unsigned r = (u + 0x7FFFu + ((u >> 16) & 1u)) >> 16;   // RNE
    return (unsigned short)r;
}
__device__ __forceinline__ unsigned short f2bf_n(float f) {
    __hip_bfloat16 h = __float2bfloat16(f);   // RNE; compiler pairs into v_cvt_pk_bf16_f32
    return *reinterpret_cast<unsigned short*>(&h);
}

#define GLDS16(gp, lp)                                                         \
    __builtin_amdgcn_global_load_lds(                                          \
        (__attribute__((address_space(1))) const void*)(gp),                   \
        (__attribute__((address_space(3))) void*)(lp), 16, 0, 0)

#define VMCNT(n) asm volatile("s_waitcnt vmcnt(" #n ")" ::: "memory")
#define LGKM0()  asm volatile("s_waitcnt lgkmcnt(0)" ::: "memory")
#define SBAR()   __builtin_amdgcn_s_barrier()
#define SCHED0() __builtin_amdgcn_sched_barrier(0)

// ===== Fused kernel: blocks 0..511 = GEMM1 (h = silu(gen@w1^T) -> bf16 H);
//       blocks 512..1023 = w2 f32->bf16 cast (grid-stride).
// (256,4): 36.8KB LDS -> 4 blocks/CU = 4 independent barrier domains
// (gemm1 was the last kernel stuck at 2 domains; same knob as r12->r13).
#define G1_B 12288
#define NB3  (DW * DGg / 4)
#define CAST_BLOCKS 512

__global__ __launch_bounds__(256, 4) void gemm1_cast_kernel(
    const float* __restrict__ gen,
    const float* __restrict__ w1,
    const float* __restrict__ w2,
    unsigned short* __restrict__ w2_b,
    unsigned short* __restrict__ H)
{
    __shared__ __attribute__((aligned(16))) char lds[36864];
    const int tid = threadIdx.x;

    if (blockIdx.x >= 512) {
        // ---- cast path: w2 f32 -> bf16, grid-stride float4 ----
        int i0 = (blockIdx.x - 512) * 256 + tid;
        for (int i = i0; i < NB3; i += CAST_BLOCKS * 256) {
            float4 v = reinterpret_cast<const float4*>(w2)[i];
            ushort4 u;
            u.x = f2bf(v.x); u.y = f2bf(v.y); u.z = f2bf(v.z); u.w = f2bf(v.w);
            reinterpret_cast<ushort4*>(w2_b)[i] = u;
        }
        return;
    }

    // ---- GEMM1 path (round-16/17 verified logic, unchanged) ----
    const int lane = tid & 63, wave = tid >> 6;
    const int wm   = wave >> 1, wn = wave & 1;
    const int la   = lane & 15, hi = lane >> 4;

    // XCD swizzle (512 blocks, %8==0 -> bijective); g fast within XCD
    int bid = blockIdx.x;
    int swz = (bid & 7) * 64 + (bid >> 3);
    const int g0 = (swz & 7) * 64;     // 8 g-tiles
    const int t0 = (swz >> 3) * 128;   // 64 t-tiles

    const int arow = tid >> 2, aslot = tid & 3;
    const int brow = tid >> 2;

    auto issue = [&](float4 (&A)[2], float4 (&B0)[2], float4 (&B1)[2], int tk) {
        const float* pa = w1 + (size_t)(g0 + arow) * DMm + tk * 32 + aslot * 8;
        A[0] = *reinterpret_cast<const float4*>(pa);
        A[1] = *reinterpret_cast<const float4*>(pa + 4);
        const float* pb0 = gen + (size_t)(t0 + brow) * DMm + tk * 32 + aslot * 8;
        B0[0] = *reinterpret_cast<const float4*>(pb0);
        B0[1] = *reinterpret_cast<const float4*>(pb0 + 4);
        const float* pb1 = gen + (size_t)(t0 + 64 + brow) * DMm + tk * 32 + aslot * 8;
        B1[0] = *reinterpret_cast<const float4*>(pb1);
        B1[1] = *reinterpret_cast<const float4*>(pb1 + 4);
    };
    auto packStore = [&](char* dst, const float4& v0, const float4& v1) {
        union { bf16x8 v; unsigned short s[8]; } u;
        u.s[0] = f2bf_n(v0.x); u.s[1] = f2bf_n(v0.y);
        u.s[2] = f2bf_n(v0.z); u.s[3] = f2bf_n(v0.w);
        u.s[4] = f2bf_n(v1.x); u.s[5] = f2bf_n(v1.y);
        u.s[6] = f2bf_n(v1.z); u.s[7] = f2bf_n(v1.w);
        *reinterpret_cast<bf16x8*>(dst) = u.v;
    };
    auto cvtWrite = [&](float4 (&A)[2], float4 (&B0)[2], float4 (&B1)[2], int p) {
        packStore(lds + p * 4096 + arow * 64 + ((aslot ^ ((arow >> 1) & 3)) * 16),
                  A[0], A[1]);
        packStore(lds + G1_B + p * 8192 + brow * 64 +
                      ((aslot ^ ((brow >> 1) & 3)) * 16), B0[0], B0[1]);
        packStore(lds + G1_B + p * 8192 + (brow + 64) * 64 +
                      ((aslot ^ (((brow + 64) >> 1) & 3)) * 16), B1[0], B1[1]);
    };

    f32x4 acc[2][4] = {};
    const int slotb = (hi ^ ((la >> 1) & 3)) * 16;
    const int aOff  = (wm * 32 + la) * 64 + slotb;
    const int bOff  = G1_B + (wn * 64 + la) * 64 + slotb;

    float4 sA0[2], sB00[2], sB01[2];
    float4 sA1[2], sB10[2], sB11[2];

    auto body = [&](int r, float4 (&IA)[2], float4 (&IB0)[2], float4 (&IB1)[2],
                    float4 (&WA)[2], float4 (&WB0)[2], float4 (&WB1)[2],
                    bool doIssue, bool doWrite, bool v6) {
        const int p = r % 3;
        const char* aB = lds + p * 4096 + aOff;
        const char* bB = lds + p * 8192 + bOff;
        bf16x8 aF[2], bF[4];
#pragma unroll
        for (int m = 0; m < 2; ++m)
            aF[m] = *reinterpret_cast<const bf16x8*>(aB + m * 1024);
#pragma unroll
        for (int nr = 0; nr < 4; ++nr)
            bF[nr] = *reinterpret_cast<const bf16x8*>(bB + nr * 1024);
        if (doIssue) issue(IA, IB0, IB1, r + 2);
        SCHED0();
        __builtin_amdgcn_s_setprio(1);
#pragma unroll
        for (int m = 0; m < 2; ++m)
#pragma unroll
            for (int nr = 0; nr < 4; ++nr)
                acc[m][nr] = __builtin_amdgcn_mfma_f32_16x16x32_bf16(
                    aF[m], bF[nr], acc[m][nr], 0, 0, 0);
        __builtin_amdgcn_s_setprio(0);
        SCHED0();
        if (doWrite) {
            if (v6) VMCNT(6); else VMCNT(0);
            cvtWrite(WA, WB0, WB1, (r + 1) % 3);
            LGKM0();
            SBAR();
        }
    };

    issue(sA0, sB00, sB01, 0);
    issue(sA1, sB10, sB11, 1);
    VMCNT(6);
    cvtWrite(sA0, sB00, sB01, 0);
    LGKM0();
    SBAR();

    for (int r = 0; r < 62; ++r) {
        if (r & 1) body(r, sA1, sB10, sB11, sA0, sB00, sB01, true, true, true);
        else       body(r, sA0, sB00, sB01, sA1, sB10, sB11, true, true, true);
    }
    body(62, sA0, sB00, sB01, sA1, sB10, sB11, false, true, false);
    body(63, sA0, sB00, sB01, sA1, sB10, sB11, false, false, false);

    __syncthreads();

    unsigned short* smY = reinterpret_cast<unsigned short*>(lds);
#pragma unroll
    for (int nr = 0; nr < 4; ++nr) {
        int tl = wn * 64 + nr * 16 + la;
#pragma unroll
        for (int m = 0; m < 2; ++m) {
            int gl0 = wm * 32 + m * 16 + hi * 4;
#pragma unroll
            for (int j = 0; j < 4; ++j) {
                float v = acc[m][nr][j];
                smY[tl * 72 + gl0 + j] = f2bf(v / (1.0f + __expf(-v)));
            }
        }
    }
    __syncthreads();

    for (int c = tid; c < 128 * 8; c += 256) {
        int row = c >> 3, q = c & 7;
        bf16x8 v = *reinterpret_cast<const bf16x8*>(&smY[row * 72 + q * 8]);
        *reinterpret_cast<bf16x8*>(&H[(size_t)(t0 + row) * DGg + g0 + q * 8]) = v;
    }
}

// ===== GEMM2 fused: 256n x 128t, 8 waves (64x64), ring-3 BK=32, 2 blk/CU =====
// (round-13/15/17 kernel VERBATIM — 180us verified.  x loads stay POST-loop:
// hoisting them to the prologue stretches xv's live range across the K-loop
// and spills to scratch at the (512,4) cap — round-16's +46us regression.)
#define LDS_B2 49152

__global__ __launch_bounds__(512, 4) void gemm2_conv_silu_kernel(
    const unsigned short* __restrict__ Hb,
    const unsigned short* __restrict__ W2b,
    const float* __restrict__ b2,
    const float* __restrict__ x,
    float* __restrict__ out)
{
    __shared__ __attribute__((aligned(16))) char lds[73728];
    const int tid  = threadIdx.x;
    const int lane = tid & 63, wave = tid >> 6;
    const int wm   = wave >> 1, wn = wave & 1;
    const int la   = lane & 15, hi = lane >> 4;

    // XCD-aware swizzle (4096 blocks, %8==0 -> bijective); t fast within XCD
    int bid = blockIdx.x;
    int swz = (bid & 7) * 512 + (bid >> 3);
    const int n0 = (swz >> 6) * 256;   // 64 n-tiles
    const int t0 = (swz & 63) * 128;   // 64 t-tiles
    const int d0 = n0 >> 2;

    const int srow = lane >> 2;                               // 0..15
    const int scol = ((lane & 3) ^ ((srow >> 1) & 3)) * 8;    // pre-swizzled src col

    auto stageA = [&](int tk, int p) {   // 2 loads/thread: 16KB tile (256 rows)
#pragma unroll
        for (int q = 0; q < 2; ++q) {
            int chunk = wave * 2 + q, row = chunk * 16 + srow;   // 0..255
            GLDS16(W2b + (size_t)(n0 + row) * DGg + tk * 32 + scol,
                   lds + p * 16384 + chunk * 1024);
        }
    };
    auto stageB = [&](int tk, int p) {   // 1 load/thread: 8KB tile (128 rows)
        int row = wave * 16 + srow;                              // 0..127
        GLDS16(Hb + (size_t)(t0 + row) * DGg + tk * 32 + scol,
               lds + LDS_B2 + p * 8192 + wave * 1024);
    };

    f32x4 acc[4][4] = {};
    const int slotb = (hi ^ ((la >> 1) & 3)) * 16;   // swizzled 16B slot
    const int aOff  = (wm * 64 + la) * 64 + slotb;
    const int bOff  = LDS_B2 + (wn * 64 + la) * 64 + slotb;

    auto region = [&](int r, bool doStage) {
        const int p = r % 3;
        const char* aB = lds + p * 16384 + aOff;
        const char* bB = lds + p * 8192 + bOff;
        bf16x8 aF[4], bF[4];
#pragma unroll
        for (int m = 0; m < 4; ++m)
            aF[m] = *reinterpret_cast<const bf16x8*>(aB + m * 1024);
#pragma unroll
        for (int nr = 0; nr < 4; ++nr)
            bF[nr] = *reinterpret_cast<const bf16x8*>(bB + nr * 1024);
        if (doStage) { stageA(r + 2, (r + 2) % 3); stageB(r + 2, (r + 2) % 3); }
        SCHED0();   // pin reads+stage above the MFMA cluster
        __builtin_amdgcn_s_setprio(1);
#pragma unroll
        for (int m = 0; m < 4; ++m)
#pragma unroll
            for (int nr = 0; nr < 4; ++nr)
                acc[m][nr] = __builtin_amdgcn_mfma_f32_16x16x32_bf16(
                    aF[m], bF[nr], acc[m][nr], 0, 0, 0);
        __builtin_amdgcn_s_setprio(0);
        SCHED0();
    };

    // ---- prologue: stage tiles 0,1 ----
    stageA(0, 0); stageB(0, 0);
    stageA(1, 1); stageB(1, 1);
    VMCNT(3);     // tile 0 certified for all waves after the barrier
    SBAR();

    // ---- main loop: 16 regions, counted vmcnt BEFORE each barrier ----
#pragma unroll
    for (int r = 0; r < 14; ++r) {
        region(r, true);
        VMCNT(3);      // certify tile r+1; tile r+2 (3 loads) in flight
        SBAR();
    }
    region(14, false); VMCNT(0); SBAR();   // certify tile 15
    region(15, false);

    // ---- x loads (post-loop; short live range -> no spill) ----
    float4 xv[5];
#pragma unroll
    for (int k = 0; k < 5; ++k) {
        int c = tid + k * 512;                   // < 2096 = 131 rows * 16 chunks
        float4 v = make_float4(0.f, 0.f, 0.f, 0.f);
        if (c < 2096) {
            int row = c >> 4, q = c & 15;
            int rg = t0 - 3 + row;
            if (rg >= 0 && (rg >> 12) == (t0 >> 12))   // zero across batch boundary
                v = *reinterpret_cast<const float4*>(&x[(size_t)rg * DD + d0 + q * 4]);
        }
        xv[k] = v;
    }
    __syncthreads();   // all K-loop LDS reads done; overlay X/Y

    float* smX = reinterpret_cast<float*>(lds);
#pragma unroll
    for (int k = 0; k < 5; ++k) {
        int c = tid + k * 512;
        if (c < 2096) {
            int row = c >> 4, q = c & 15;
            *reinterpret_cast<float4*>(&smX[row * 68 + q * 4]) = xv[k];
        }
    }
    __syncthreads();

    // ---- epilogue: bias + conv taps (reg idx j) + silu -> smY ----
    float4 bb[4];
#pragma unroll
    for (int m = 0; m < 4; ++m)
        bb[m] = *reinterpret_cast<const float4*>(&b2[n0 + wm * 64 + m * 16 + hi * 4]);

    float* smY = reinterpret_cast<float*>(lds + 35632);
#pragma unroll
    for (int nr = 0; nr < 4; ++nr) {
        int tl = wn * 64 + nr * 16 + la;
#pragma unroll
        for (int m = 0; m < 4; ++m) {
            int dl = wm * 16 + m * 4 + hi;
            float pv =
                  (acc[m][nr][0] + bb[m].x) * smX[(tl + 0) * 68 + dl]
                + (acc[m][nr][1] + bb[m].y) * smX[(tl + 1) * 68 + dl]
                + (acc[m][nr][2] + bb[m].z) * smX[(tl + 2) * 68 + dl]
                + (acc[m][nr][3] + bb[m].w) * smX[(tl + 3) * 68 + dl];
            smY[tl * 68 + dl] = pv / (1.0f + __expf(-pv));
        }
    }
    __syncthreads();

    // ---- coalesced store: 128 rows x 64 f32 (256 B per row) ----
    for (int c = tid; c < 128 * 16; c += 512) {
        int row = c >> 4, q = c & 15;
        float4 v = *reinterpret_cast<const float4*>(&smY[row * 68 + q * 4]);
        *reinterpret_cast<float4*>(&out[(size_t)(t0 + row) * DD + d0 + q * 4]) = v;
    }
}

extern "C" void kernel_launch(void* const* d_in, const int* in_sizes, int n_in,
                              void* d_out, int out_size, void* d_ws, size_t ws_size,
                              hipStream_t stream) {
    const float* x   = (const float*)d_in[0];
    const float* gen = (const float*)d_in[1];
    const float* w1  = (const float*)d_in[2];
    const float* w2  = (const float*)d_in[3];
    const float* b2  = (const float*)d_in[4];
    float* out = (float*)d_out;

    char* ws = (char*)d_ws;
    size_t off = 0;
    unsigned short* w2_b = (unsigned short*)(ws + off); off += (size_t)DW * DGg * 2;
    unsigned short* h_b  = (unsigned short*)(ws + off); off += (size_t)BT * DGg * 2;

    gemm1_cast_kernel<<<512 + CAST_BLOCKS, 256, 0, stream>>>(gen, w1, w2, w2_b, h_b);
    gemm2_conv_silu_kernel<<<4096, 512, 0, stream>>>(h_b, w2_b, b2, x, out);
}

// Round 20
// 234.204 us; speedup vs baseline: 2.7069x; 2.7069x over previous
//
#include <hip/hip_runtime.h>
#include <hip/hip_bf16.h>
#include <stdint.h>

// Problem constants
#define TLEN 4096
#define DMm  2048
#define DD   4096
#define DGg  512
#define BT   8192          // B*T
#define DW   16384         // D*W

typedef __attribute__((ext_vector_type(8))) short bf16x8;
typedef __attribute__((ext_vector_type(4))) float f32x4;

__device__ __forceinline__ unsigned short f2bf(float f) {
    union { float f; unsigned u; } c; c.f = f;
    unsigned u = c.u;
    unsigned r = (u + 0x7FFFu + ((u >> 16) & 1u)) >> 16;   // RNE
    return (unsigned short)r;
}
__device__ __forceinline__ unsigned short f2bf_n(float f) {
    __hip_bfloat16 h = __float2bfloat16(f);   // RNE; compiler pairs into v_cvt_pk_bf16_f32
    return *reinterpret_cast<unsigned short*>(&h);
}

#define GLDS16(gp, lp)                                                         \
    __builtin_amdgcn_global_load_lds(                                          \
        (__attribute__((address_space(1))) const void*)(gp),                   \
        (__attribute__((address_space(3))) void*)(lp), 16, 0, 0)

#define VMCNT(n) asm volatile("s_waitcnt vmcnt(" #n ")" ::: "memory")
#define LGKM0()  asm volatile("s_waitcnt lgkmcnt(0)" ::: "memory")
#define SBAR()   __builtin_amdgcn_s_barrier()
#define SCHED0() __builtin_amdgcn_sched_barrier(0)

// ===== Fused kernel: blocks 0..511 = GEMM1 (h = silu(gen@w1^T) -> bf16 H);
//       blocks 512..1023 = w2 f32->bf16 cast (grid-stride).
// (256,2): gemm1's T14 reg-staging needs ~110 VGPR -> incompatible with
// 4 waves/SIMD (round-19: (256,4) halved the register target and spilled,
// WRITE_SIZE 986MB, 505us).  Keep 2 blocks/CU.
#define G1_B 12288
#define NB3  (DW * DGg / 4)
#define CAST_BLOCKS 512

__global__ __launch_bounds__(256, 2) void gemm1_cast_kernel(
    const float* __restrict__ gen,
    const float* __restrict__ w1,
    const float* __restrict__ w2,
    unsigned short* __restrict__ w2_b,
    unsigned short* __restrict__ H)
{
    __shared__ __attribute__((aligned(16))) char lds[36864];
    const int tid = threadIdx.x;

    if (blockIdx.x >= 512) {
        // ---- cast path: w2 f32 -> bf16, grid-stride float4 ----
        int i0 = (blockIdx.x - 512) * 256 + tid;
        for (int i = i0; i < NB3; i += CAST_BLOCKS * 256) {
            float4 v = reinterpret_cast<const float4*>(w2)[i];
            ushort4 u;
            u.x = f2bf(v.x); u.y = f2bf(v.y); u.z = f2bf(v.z); u.w = f2bf(v.w);
            reinterpret_cast<ushort4*>(w2_b)[i] = u;
        }
        return;
    }

    // ---- GEMM1 path (round-16/17 verified logic, unchanged) ----
    const int lane = tid & 63, wave = tid >> 6;
    const int wm   = wave >> 1, wn = wave & 1;
    const int la   = lane & 15, hi = lane >> 4;

    // XCD swizzle (512 blocks, %8==0 -> bijective); g fast within XCD
    int bid = blockIdx.x;
    int swz = (bid & 7) * 64 + (bid >> 3);
    const int g0 = (swz & 7) * 64;     // 8 g-tiles
    const int t0 = (swz >> 3) * 128;   // 64 t-tiles

    const int arow = tid >> 2, aslot = tid & 3;
    const int brow = tid >> 2;

    auto issue = [&](float4 (&A)[2], float4 (&B0)[2], float4 (&B1)[2], int tk) {
        const float* pa = w1 + (size_t)(g0 + arow) * DMm + tk * 32 + aslot * 8;
        A[0] = *reinterpret_cast<const float4*>(pa);
        A[1] = *reinterpret_cast<const float4*>(pa + 4);
        const float* pb0 = gen + (size_t)(t0 + brow) * DMm + tk * 32 + aslot * 8;
        B0[0] = *reinterpret_cast<const float4*>(pb0);
        B0[1] = *reinterpret_cast<const float4*>(pb0 + 4);
        const float* pb1 = gen + (size_t)(t0 + 64 + brow) * DMm + tk * 32 + aslot * 8;
        B1[0] = *reinterpret_cast<const float4*>(pb1);
        B1[1] = *reinterpret_cast<const float4*>(pb1 + 4);
    };
    auto packStore = [&](char* dst, const float4& v0, const float4& v1) {
        union { bf16x8 v; unsigned short s[8]; } u;
        u.s[0] = f2bf_n(v0.x); u.s[1] = f2bf_n(v0.y);
        u.s[2] = f2bf_n(v0.z); u.s[3] = f2bf_n(v0.w);
        u.s[4] = f2bf_n(v1.x); u.s[5] = f2bf_n(v1.y);
        u.s[6] = f2bf_n(v1.z); u.s[7] = f2bf_n(v1.w);
        *reinterpret_cast<bf16x8*>(dst) = u.v;
    };
    auto cvtWrite = [&](float4 (&A)[2], float4 (&B0)[2], float4 (&B1)[2], int p) {
        packStore(lds + p * 4096 + arow * 64 + ((aslot ^ ((arow >> 1) & 3)) * 16),
                  A[0], A[1]);
        packStore(lds + G1_B + p * 8192 + brow * 64 +
                      ((aslot ^ ((brow >> 1) & 3)) * 16), B0[0], B0[1]);
        packStore(lds + G1_B + p * 8192 + (brow + 64) * 64 +
                      ((aslot ^ (((brow + 64) >> 1) & 3)) * 16), B1[0], B1[1]);
    };

    f32x4 acc[2][4] = {};
    const int slotb = (hi ^ ((la >> 1) & 3)) * 16;
    const int aOff  = (wm * 32 + la) * 64 + slotb;
    const int bOff  = G1_B + (wn * 64 + la) * 64 + slotb;

    float4 sA0[2], sB00[2], sB01[2];
    float4 sA1[2], sB10[2], sB11[2];

    auto body = [&](int r, float4 (&IA)[2], float4 (&IB0)[2], float4 (&IB1)[2],
                    float4 (&WA)[2], float4 (&WB0)[2], float4 (&WB1)[2],
                    bool doIssue, bool doWrite, bool v6) {
        const int p = r % 3;
        const char* aB = lds + p * 4096 + aOff;
        const char* bB = lds + p * 8192 + bOff;
        bf16x8 aF[2], bF[4];
#pragma unroll
        for (int m = 0; m < 2; ++m)
            aF[m] = *reinterpret_cast<const bf16x8*>(aB + m * 1024);
#pragma unroll
        for (int nr = 0; nr < 4; ++nr)
            bF[nr] = *reinterpret_cast<const bf16x8*>(bB + nr * 1024);
        if (doIssue) issue(IA, IB0, IB1, r + 2);
        SCHED0();
        __builtin_amdgcn_s_setprio(1);
#pragma unroll
        for (int m = 0; m < 2; ++m)
#pragma unroll
            for (int nr = 0; nr < 4; ++nr)
                acc[m][nr] = __builtin_amdgcn_mfma_f32_16x16x32_bf16(
                    aF[m], bF[nr], acc[m][nr], 0, 0, 0);
        __builtin_amdgcn_s_setprio(0);
        SCHED0();
        if (doWrite) {
            if (v6) VMCNT(6); else VMCNT(0);
            cvtWrite(WA, WB0, WB1, (r + 1) % 3);
            LGKM0();
            SBAR();
        }
    };

    issue(sA0, sB00, sB01, 0);
    issue(sA1, sB10, sB11, 1);
    VMCNT(6);
    cvtWrite(sA0, sB00, sB01, 0);
    LGKM0();
    SBAR();

    for (int r = 0; r < 62; ++r) {
        if (r & 1) body(r, sA1, sB10, sB11, sA0, sB00, sB01, true, true, true);
        else       body(r, sA0, sB00, sB01, sA1, sB10, sB11, true, true, true);
    }
    body(62, sA0, sB00, sB01, sA1, sB10, sB11, false, true, false);
    body(63, sA0, sB00, sB01, sA1, sB10, sB11, false, false, false);

    __syncthreads();

    unsigned short* smY = reinterpret_cast<unsigned short*>(lds);
#pragma unroll
    for (int nr = 0; nr < 4; ++nr) {
        int tl = wn * 64 + nr * 16 + la;
#pragma unroll
        for (int m = 0; m < 2; ++m) {
            int gl0 = wm * 32 + m * 16 + hi * 4;
#pragma unroll
            for (int j = 0; j < 4; ++j) {
                float v = acc[m][nr][j];
                smY[tl * 72 + gl0 + j] = f2bf(v / (1.0f + __expf(-v)));
            }
        }
    }
    __syncthreads();

    for (int c = tid; c < 128 * 8; c += 256) {
        int row = c >> 3, q = c & 7;
        bf16x8 v = *reinterpret_cast<const bf16x8*>(&smY[row * 72 + q * 8]);
        *reinterpret_cast<bf16x8*>(&H[(size_t)(t0 + row) * DGg + g0 + q * 8]) = v;
    }
}

// ===== GEMM2 fused: 256n x 128t, 8 waves (64x64), ring-3 BK=32, 2 blk/CU =====
// (round-13/15/17 kernel VERBATIM — 180us verified.  x loads stay POST-loop:
// hoisting them to the prologue stretches xv's live range across the K-loop
// and spills to scratch at the (512,4) cap — round-16's +46us regression.)
#define LDS_B2 49152

__global__ __launch_bounds__(512, 4) void gemm2_conv_silu_kernel(
    const unsigned short* __restrict__ Hb,
    const unsigned short* __restrict__ W2b,
    const float* __restrict__ b2,
    const float* __restrict__ x,
    float* __restrict__ out)
{
    __shared__ __attribute__((aligned(16))) char lds[73728];
    const int tid  = threadIdx.x;
    const int lane = tid & 63, wave = tid >> 6;
    const int wm   = wave >> 1, wn = wave & 1;
    const int la   = lane & 15, hi = lane >> 4;

    // XCD-aware swizzle (4096 blocks, %8==0 -> bijective); t fast within XCD
    int bid = blockIdx.x;
    int swz = (bid & 7) * 512 + (bid >> 3);
    const int n0 = (swz >> 6) * 256;   // 64 n-tiles
    const int t0 = (swz & 63) * 128;   // 64 t-tiles
    const int d0 = n0 >> 2;

    const int srow = lane >> 2;                               // 0..15
    const int scol = ((lane & 3) ^ ((srow >> 1) & 3)) * 8;    // pre-swizzled src col

    auto stageA = [&](int tk, int p) {   // 2 loads/thread: 16KB tile (256 rows)
#pragma unroll
        for (int q = 0; q < 2; ++q) {
            int chunk = wave * 2 + q, row = chunk * 16 + srow;   // 0..255
            GLDS16(W2b + (size_t)(n0 + row) * DGg + tk * 32 + scol,
                   lds + p * 16384 + chunk * 1024);
        }
    };
    auto stageB = [&](int tk, int p) {   // 1 load/thread: 8KB tile (128 rows)
        int row = wave * 16 + srow;                              // 0..127
        GLDS16(Hb + (size_t)(t0 + row) * DGg + tk * 32 + scol,
               lds + LDS_B2 + p * 8192 + wave * 1024);
    };

    f32x4 acc[4][4] = {};
    const int slotb = (hi ^ ((la >> 1) & 3)) * 16;   // swizzled 16B slot
    const int aOff  = (wm * 64 + la) * 64 + slotb;
    const int bOff  = LDS_B2 + (wn * 64 + la) * 64 + slotb;

    auto region = [&](int r, bool doStage) {
        const int p = r % 3;
        const char* aB = lds + p * 16384 + aOff;
        const char* bB = lds + p * 8192 + bOff;
        bf16x8 aF[4], bF[4];
#pragma unroll
        for (int m = 0; m < 4; ++m)
            aF[m] = *reinterpret_cast<const bf16x8*>(aB + m * 1024);
#pragma unroll
        for (int nr = 0; nr < 4; ++nr)
            bF[nr] = *reinterpret_cast<const bf16x8*>(bB + nr * 1024);
        if (doStage) { stageA(r + 2, (r + 2) % 3); stageB(r + 2, (r + 2) % 3); }
        SCHED0();   // pin reads+stage above the MFMA cluster
        __builtin_amdgcn_s_setprio(1);
#pragma unroll
        for (int m = 0; m < 4; ++m)
#pragma unroll
            for (int nr = 0; nr < 4; ++nr)
                acc[m][nr] = __builtin_amdgcn_mfma_f32_16x16x32_bf16(
                    aF[m], bF[nr], acc[m][nr], 0, 0, 0);
        __builtin_amdgcn_s_setprio(0);
        SCHED0();
    };

    // ---- prologue: stage tiles 0,1 ----
    stageA(0, 0); stageB(0, 0);
    stageA(1, 1); stageB(1, 1);
    VMCNT(3);     // tile 0 certified for all waves after the barrier
    SBAR();

    // ---- main loop: 16 regions, counted vmcnt BEFORE each barrier ----
#pragma unroll
    for (int r = 0; r < 14; ++r) {
        region(r, true);
        VMCNT(3);      // certify tile r+1; tile r+2 (3 loads) in flight
        SBAR();
    }
    region(14, false); VMCNT(0); SBAR();   // certify tile 15
    region(15, false);

    // ---- x loads (post-loop; short live range -> no spill) ----
    float4 xv[5];
#pragma unroll
    for (int k = 0; k < 5; ++k) {
        int c = tid + k * 512;                   // < 2096 = 131 rows * 16 chunks
        float4 v = make_float4(0.f, 0.f, 0.f, 0.f);
        if (c < 2096) {
            int row = c >> 4, q = c & 15;
            int rg = t0 - 3 + row;
            if (rg >= 0 && (rg >> 12) == (t0 >> 12))   // zero across batch boundary
                v = *reinterpret_cast<const float4*>(&x[(size_t)rg * DD + d0 + q * 4]);
        }
        xv[k] = v;
    }
    __syncthreads();   // all K-loop LDS reads done; overlay X/Y

    float* smX = reinterpret_cast<float*>(lds);
#pragma unroll
    for (int k = 0; k < 5; ++k) {
        int c = tid + k * 512;
        if (c < 2096) {
            int row = c >> 4, q = c & 15;
            *reinterpret_cast<float4*>(&smX[row * 68 + q * 4]) = xv[k];
        }
    }
    __syncthreads();

    // ---- epilogue: bias + conv taps (reg idx j) + silu -> smY ----
    float4 bb[4];
#pragma unroll
    for (int m = 0; m < 4; ++m)
        bb[m] = *reinterpret_cast<const float4*>(&b2[n0 + wm * 64 + m * 16 + hi * 4]);

    float* smY = reinterpret_cast<float*>(lds + 35632);
#pragma unroll
    for (int nr = 0; nr < 4; ++nr) {
        int tl = wn * 64 + nr * 16 + la;
#pragma unroll
        for (int m = 0; m < 4; ++m) {
            int dl = wm * 16 + m * 4 + hi;
            float pv =
                  (acc[m][nr][0] + bb[m].x) * smX[(tl + 0) * 68 + dl]
                + (acc[m][nr][1] + bb[m].y) * smX[(tl + 1) * 68 + dl]
                + (acc[m][nr][2] + bb[m].z) * smX[(tl + 2) * 68 + dl]
                + (acc[m][nr][3] + bb[m].w) * smX[(tl + 3) * 68 + dl];
            smY[tl * 68 + dl] = pv / (1.0f + __expf(-pv));
        }
    }
    __syncthreads();

    // ---- coalesced store: 128 rows x 64 f32 (256 B per row) ----
    for (int c = tid; c < 128 * 16; c += 512) {
        int row = c >> 4, q = c & 15;
        float4 v = *reinterpret_cast<const float4*>(&smY[row * 68 + q * 4]);
        *reinterpret_cast<float4*>(&out[(size_t)(t0 + row) * DD + d0 + q * 4]) = v;
    }
}

extern "C" void kernel_launch(void* const* d_in, const int* in_sizes, int n_in,
                              void* d_out, int out_size, void* d_ws, size_t ws_size,
                              hipStream_t stream) {
    const float* x   = (const float*)d_in[0];
    const float* gen = (const float*)d_in[1];
    const float* w1  = (const float*)d_in[2];
    const float* w2  = (const float*)d_in[3];
    const float* b2  = (const float*)d_in[4];
    float* out = (float*)d_out;

    char* ws = (char*)d_ws;
    size_t off = 0;
    unsigned short* w2_b = (unsigned short*)(ws + off); off += (size_t)DW * DGg * 2;
    unsigned short* h_b  = (unsigned short*)(ws + off); off += (size_t)BT * DGg * 2;

    gemm1_cast_kernel<<<512 + CAST_BLOCKS, 256, 0, stream>>>(gen, w1, w2, w2_b, h_b);
    gemm2_conv_silu_kernel<<<4096, 512, 0, stream>>>(h_b, w2_b, b2, x, out);
}